// Round 6
// baseline (2994.179 us; speedup 1.0000x reference)
//
#include <hip/hip_runtime.h>

// VanillaLSTM fused, round 4 kernel, resubmit #2 (rounds 4 and 5 both died in
// GPU acquisition; kernel never ran). Weights staged in LDS (12.5 KB), read
// via ds_read_b128/b64 at base+immediate offsets (no per-load address math,
// no readfirstlane, VGPR-budget pipelining). MACs stay v_pk_fma_f32 (2 seqs
// per lane) with "v" weight source; gate-major ordering spaces
// same-accumulator deps by 4 instructions.

typedef float v2f __attribute__((ext_vector_type(2)));
typedef float v4f __attribute__((ext_vector_type(4)));

#define TSTEPS 64
#define H 20
#define M 10

static __device__ __forceinline__ v2f sp(float s){ v2f r; r.x = s; r.y = s; return r; }
static __device__ __forceinline__ v2f mk(float a, float b){ v2f r; r.x = a; r.y = b; return r; }
static __device__ __forceinline__ v2f lo2(v4f w){ v2f r; r.x = w.x; r.y = w.y; return r; }
static __device__ __forceinline__ v2f hi2(v4f w){ v2f r; r.x = w.z; r.y = w.w; return r; }

// acc.xy += w.x * v.xy   (broadcast LOW word of VGPR pair)
static __device__ __forceinline__ void pk_lo(v2f& acc, v2f w, v2f v){
    asm("v_pk_fma_f32 %0, %1, %2, %0 op_sel:[0,0,0] op_sel_hi:[0,1,1]"
        : "+v"(acc) : "v"(w), "v"(v));
}
// acc.xy += w.y * v.xy   (broadcast HIGH word)
static __device__ __forceinline__ void pk_hi(v2f& acc, v2f w, v2f v){
    asm("v_pk_fma_f32 %0, %1, %2, %0 op_sel:[1,0,0] op_sel_hi:[1,1,1]"
        : "+v"(acc) : "v"(w), "v"(v));
}

// 4 gates x 4 consecutive k. Gate-major: same-acc deps spaced by 4 instrs.
#define MAC_QUAD(wi,wf,wg,wo,v0,v1,v2,v3) do{                               \
    v4f _wi=(wi), _wf=(wf), _wg=(wg), _wo=(wo);                             \
    v2f _i01=lo2(_wi), _f01=lo2(_wf), _g01=lo2(_wg), _o01=lo2(_wo);         \
    v2f _i23=hi2(_wi), _f23=hi2(_wf), _g23=hi2(_wg), _o23=hi2(_wo);         \
    pk_lo(ai,_i01,v0); pk_lo(af,_f01,v0); pk_lo(ag,_g01,v0); pk_lo(ao,_o01,v0); \
    pk_hi(ai,_i01,v1); pk_hi(af,_f01,v1); pk_hi(ag,_g01,v1); pk_hi(ao,_o01,v1); \
    pk_lo(ai,_i23,v2); pk_lo(af,_f23,v2); pk_lo(ag,_g23,v2); pk_lo(ao,_o23,v2); \
    pk_hi(ai,_i23,v3); pk_hi(af,_f23,v3); pk_hi(ag,_g23,v3); pk_hi(ao,_o23,v3); \
}while(0)

static __device__ __forceinline__ float sigm1(float x){
    return __builtin_amdgcn_rcpf(1.0f + __expf(-x));
}
static __device__ __forceinline__ v2f sigm(v2f x){ return mk(sigm1(x.x), sigm1(x.y)); }
static __device__ __forceinline__ float tanh1(float x){
    return 1.0f - 2.0f * __builtin_amdgcn_rcpf(__expf(2.0f * x) + 1.0f);
}
static __device__ __forceinline__ v2f tanhv(v2f x){ return mk(tanh1(x.x), tanh1(x.y)); }

__global__ __launch_bounds__(256)
void lstm_fused(const float* __restrict__ X,
                const int*   __restrict__ pm,
                const float* __restrict__ h0,
                const float* __restrict__ c0,
                const float* __restrict__ Yv,
                const int*   __restrict__ tobs_p,
                const int*   __restrict__ tpred_p,
                const float* __restrict__ W_in,  const float* __restrict__ b_in,
                const float* __restrict__ W_ih,  const float* __restrict__ W_hh,
                const float* __restrict__ b_ih,  const float* __restrict__ b_hh,
                const float* __restrict__ W_out, const float* __restrict__ b_out,
                float* __restrict__ outp, int N)
{
    // ---- LDS-staged weights (rows 16B-aligned; biases pre-summed & dup'd) ----
    __shared__ v4f s_wih[4*H][4];     // W_ih rows padded 10 -> 16 floats
    __shared__ v4f s_whh[4*H][5];     // W_hh rows, 20 floats = 5 quads
    __shared__ v2f s_bias2[4*H];      // {b_ih+b_hh, b_ih+b_hh}
    __shared__ v2f s_win[M];          // W_in row = 2 floats
    __shared__ v2f s_bin2[M];         // {b_in, b_in}
    __shared__ v2f s_wout[2][M];      // row r, pair (2k, 2k+1)
    __shared__ v2f s_bout2[2];        // {b_out, b_out}

    const int lt = threadIdx.x;
    {
        float* f_wih = (float*)s_wih;
        for (int i = lt; i < 4*H*16; i += 256){
            int rr = i >> 4, kk = i & 15;
            f_wih[i] = (kk < M) ? W_ih[rr*M + kk] : 0.f;
        }
        float* f_whh = (float*)s_whh;
        for (int i = lt; i < 4*H*H; i += 256) f_whh[i] = W_hh[i];
        if (lt < 4*H){ float s = b_ih[lt] + b_hh[lt]; s_bias2[lt] = mk(s, s); }
        if (lt < M){ s_win[lt] = mk(W_in[lt*2], W_in[lt*2+1]);
                     float bb = b_in[lt]; s_bin2[lt] = mk(bb, bb); }
        if (lt < 2*M){ int rr = lt / M, k2 = lt % M;
                       s_wout[rr][k2] = mk(W_out[rr*H + 2*k2], W_out[rr*H + 2*k2 + 1]); }
        if (lt < 2){ float bb = b_out[lt]; s_bout2[lt] = mk(bb, bb); }
    }
    __syncthreads();

    const int tid  = blockIdx.x * blockDim.x + lt;
    const int half = N >> 1;
    if (tid >= half) return;          // no barriers after this point
    const int n0 = tid;               // lane's sequence A
    const int n1 = tid + half;        // lane's sequence B
    const int T_obs  = *tobs_p;
    const int T_pred = *tpred_p;
    const int tmax   = (T_pred < TSTEPS - 1) ? T_pred : (TSTEPS - 1);

    // recurrent state in registers (packed: .x = seq A, .y = seq B)
    v2f h[H], c[H];
#pragma unroll
    for (int j = 0; j < H; ++j){
        h[j] = mk(h0[(size_t)n0*H + j], h0[(size_t)n1*H + j]);
        c[j] = mk(c0[(size_t)n0*H + j], c0[(size_t)n1*H + j]);
    }

    v2f q0 = sp(1.f), q1 = sp(1.f), q2 = sp(1.f);   // m_prev3 rolling queue
    v2f po0 = sp(0.f), po1 = sp(0.f);               // prev output

    int pm0 = pm[n0];
    int pm1 = pm[n1];
    v2f x0, x1;
    {
        v2f xa = *(const v2f*)(X + ((size_t)0*N + n0)*4 + 2);
        v2f xb = *(const v2f*)(X + ((size_t)0*N + n1)*4 + 2);
        x0 = mk(xa.x, xb.x);
        x1 = mk(xa.y, xb.y);
    }

#pragma unroll 1
    for (int t = 0; t <= tmax; ++t){
        const v2f mt  = mk((float)pm0, (float)pm1);
        const v2f mp3 = q0; q0 = q1; q1 = q2; q2 = mt;

        v2f in0, in1;
        if (t <= T_obs){ in0 = x0; in1 = x1; }       // uniform branch
        else           { in0 = po0; in1 = po1; }

        // prefetch next step's mask / X
        if (t < tmax){
            pm0 = pm[(size_t)(t+1)*N + n0];
            pm1 = pm[(size_t)(t+1)*N + n1];
            if (t + 1 <= T_obs){
                v2f xa = *(const v2f*)(X + ((size_t)(t+1)*N + n0)*4 + 2);
                v2f xb = *(const v2f*)(X + ((size_t)(t+1)*N + n1)*4 + 2);
                x0 = mk(xa.x, xb.x);
                x1 = mk(xa.y, xb.y);
            }
        }

        // early Y fetch for overwrite lanes
        const bool ow_u = (t > 3) && (t > T_obs);
        bool ow_a = false, ow_b = false;
        v2f y0 = sp(0.f), y1 = sp(0.f);
        if (ow_u){
            ow_a = (mt.x != 0.f) && (mp3.x == 0.f);
            ow_b = (mt.y != 0.f) && (mp3.y == 0.f);
            if (ow_a){ v2f ya = *(const v2f*)(Yv + ((size_t)t*N + n0)*2); y0.x = ya.x; y1.x = ya.y; }
            if (ow_b){ v2f yb = *(const v2f*)(Yv + ((size_t)t*N + n1)*2); y0.y = yb.x; y1.y = yb.y; }
        }

        // ---- r = relu(inp @ W_in.T + b_in) ----
        v2f r[M];
#pragma unroll
        for (int mm = 0; mm < M; ++mm){
            v2f a = s_bin2[mm];
            v2f w = s_win[mm];                   // ds_read_b64
            pk_lo(a, w, in0);
            pk_hi(a, w, in1);
            r[mm] = mk(fmaxf(a.x, 0.f), fmaxf(a.y, 0.f));
        }

        // ---- gates + cell update (fully unrolled; LDS imm-offset reads) ----
        v2f hn[H];
#pragma unroll
        for (int jj = 0; jj < H; ++jj){
            v2f ai = s_bias2[jj];
            v2f af = s_bias2[H + jj];
            v2f ag = s_bias2[2*H + jj];
            v2f ao = s_bias2[3*H + jj];

            // W_ih: k = 0..7 (two quads), then k = 8,9 (b64 tail)
            MAC_QUAD(s_wih[jj][0], s_wih[H+jj][0], s_wih[2*H+jj][0], s_wih[3*H+jj][0],
                     r[0], r[1], r[2], r[3]);
            MAC_QUAD(s_wih[jj][1], s_wih[H+jj][1], s_wih[2*H+jj][1], s_wih[3*H+jj][1],
                     r[4], r[5], r[6], r[7]);
            {
                v2f wi = *(const v2f*)&s_wih[jj][2];
                v2f wf = *(const v2f*)&s_wih[H+jj][2];
                v2f wg = *(const v2f*)&s_wih[2*H+jj][2];
                v2f wo = *(const v2f*)&s_wih[3*H+jj][2];
                pk_lo(ai,wi,r[8]); pk_lo(af,wf,r[8]); pk_lo(ag,wg,r[8]); pk_lo(ao,wo,r[8]);
                pk_hi(ai,wi,r[9]); pk_hi(af,wf,r[9]); pk_hi(ag,wg,r[9]); pk_hi(ao,wo,r[9]);
            }
            // W_hh: k = 0..19, five quads
            MAC_QUAD(s_whh[jj][0], s_whh[H+jj][0], s_whh[2*H+jj][0], s_whh[3*H+jj][0],
                     h[0], h[1], h[2], h[3]);
            MAC_QUAD(s_whh[jj][1], s_whh[H+jj][1], s_whh[2*H+jj][1], s_whh[3*H+jj][1],
                     h[4], h[5], h[6], h[7]);
            MAC_QUAD(s_whh[jj][2], s_whh[H+jj][2], s_whh[2*H+jj][2], s_whh[3*H+jj][2],
                     h[8], h[9], h[10], h[11]);
            MAC_QUAD(s_whh[jj][3], s_whh[H+jj][3], s_whh[2*H+jj][3], s_whh[3*H+jj][3],
                     h[12], h[13], h[14], h[15]);
            MAC_QUAD(s_whh[jj][4], s_whh[H+jj][4], s_whh[2*H+jj][4], s_whh[3*H+jj][4],
                     h[16], h[17], h[18], h[19]);

            const v2f cn = sigm(af) * c[jj] + sigm(ai) * tanhv(ag);
            const v2f hv = sigm(ao) * tanhv(cn);
            c[jj]  = cn;          // loop only covers active steps
            hn[jj] = hv;
        }

        // ---- out = (h_new @ W_out.T + b_out) * m ----
        v2f o0 = s_bout2[0], o1 = s_bout2[1];
#pragma unroll
        for (int k2 = 0; k2 < M; ++k2){
            v2f w0 = s_wout[0][k2];
            v2f w1 = s_wout[1][k2];
            const v2f ha = hn[2*k2], hb = hn[2*k2+1];
            pk_lo(o0, w0, ha); pk_lo(o1, w1, ha);
            pk_hi(o0, w0, hb); pk_hi(o1, w1, hb);
        }
        o0 *= mt; o1 *= mt;

        if (ow_a){ o0.x = y0.x; o1.x = y1.x; }
        if (ow_b){ o0.y = y0.y; o1.y = y1.y; }

#pragma unroll
        for (int j = 0; j < H; ++j) h[j] = hn[j];

        *(v2f*)(outp + ((size_t)t*N + n0)*2) = mk(o0.x, o1.x);
        *(v2f*)(outp + ((size_t)t*N + n1)*2) = mk(o0.y, o1.y);
        po0 = o0; po1 = o1;
    }

    // tail: reference zeroes outputs for t > T_pred
#pragma unroll 1
    for (int t = tmax + 1; t < TSTEPS; ++t){
        *(v2f*)(outp + ((size_t)t*N + n0)*2) = sp(0.f);
        *(v2f*)(outp + ((size_t)t*N + n1)*2) = sp(0.f);
    }
}

extern "C" void kernel_launch(void* const* d_in, const int* in_sizes, int n_in,
                              void* d_out, int out_size, void* d_ws, size_t ws_size,
                              hipStream_t stream)
{
    const float* X     = (const float*)d_in[0];
    const int*   pmk   = (const int*)  d_in[1];
    const float* h0    = (const float*)d_in[2];
    const float* c0    = (const float*)d_in[3];
    const float* Yv    = (const float*)d_in[4];
    const int*   tobs  = (const int*)  d_in[5];
    const int*   tpred = (const int*)  d_in[6];
    const float* W_in  = (const float*)d_in[7];
    const float* b_in  = (const float*)d_in[8];
    const float* W_ih  = (const float*)d_in[9];
    const float* W_hh  = (const float*)d_in[10];
    const float* b_ih  = (const float*)d_in[11];
    const float* b_hh  = (const float*)d_in[12];
    const float* W_out = (const float*)d_in[13];
    const float* b_out = (const float*)d_in[14];
    float* outp = (float*)d_out;

    const int N = in_sizes[1] / TSTEPS;   // part_masks is (T,1,N)
    const int threads = N / 2;            // 2 sequences per thread (packed fp32)
    const int block = 256;
    const int grid = (threads + block - 1) / block;

    hipLaunchKernelGGL(lstm_fused, dim3(grid), dim3(block), 0, stream,
                       X, pmk, h0, c0, Yv, tobs, tpred,
                       W_in, b_in, W_ih, W_hh, b_ih, b_hh, W_out, b_out,
                       outp, N);
}

// Round 7
// 1049.057 us; speedup vs baseline: 2.8542x; 2.8542x over previous
//
#include <hip/hip_runtime.h>

// VanillaLSTM fused, round 7: round-6 showed LICM hoisted the loop-invariant
// LDS weight reads into registers -> 256-VGPR spill -> 5.85 GB of scratch
// re-reads (FETCH tell). Fix: launder a zero index through empty asm each
// t-iteration and derive ALL LDS bases from it, forcing per-step ds_read
// (wave-uniform broadcast, conflict-free) and keeping VGPRs for state.

typedef float v2f __attribute__((ext_vector_type(2)));
typedef float v4f __attribute__((ext_vector_type(4)));

#define TSTEPS 64
#define H 20
#define M 10

static __device__ __forceinline__ v2f sp(float s){ v2f r; r.x = s; r.y = s; return r; }
static __device__ __forceinline__ v2f mk(float a, float b){ v2f r; r.x = a; r.y = b; return r; }
static __device__ __forceinline__ v2f lo2(v4f w){ v2f r; r.x = w.x; r.y = w.y; return r; }
static __device__ __forceinline__ v2f hi2(v4f w){ v2f r; r.x = w.z; r.y = w.w; return r; }

// acc.xy += w.x * v.xy   (broadcast LOW word of VGPR pair)
static __device__ __forceinline__ void pk_lo(v2f& acc, v2f w, v2f v){
    asm("v_pk_fma_f32 %0, %1, %2, %0 op_sel:[0,0,0] op_sel_hi:[0,1,1]"
        : "+v"(acc) : "v"(w), "v"(v));
}
// acc.xy += w.y * v.xy   (broadcast HIGH word)
static __device__ __forceinline__ void pk_hi(v2f& acc, v2f w, v2f v){
    asm("v_pk_fma_f32 %0, %1, %2, %0 op_sel:[1,0,0] op_sel_hi:[1,1,1]"
        : "+v"(acc) : "v"(w), "v"(v));
}

// 4 gates x 4 consecutive k. Gate-major: same-acc deps spaced by 4 instrs.
#define MAC_QUAD(wi,wf,wg,wo,v0,v1,v2,v3) do{                               \
    v4f _wi=(wi), _wf=(wf), _wg=(wg), _wo=(wo);                             \
    v2f _i01=lo2(_wi), _f01=lo2(_wf), _g01=lo2(_wg), _o01=lo2(_wo);         \
    v2f _i23=hi2(_wi), _f23=hi2(_wf), _g23=hi2(_wg), _o23=hi2(_wo);         \
    pk_lo(ai,_i01,v0); pk_lo(af,_f01,v0); pk_lo(ag,_g01,v0); pk_lo(ao,_o01,v0); \
    pk_hi(ai,_i01,v1); pk_hi(af,_f01,v1); pk_hi(ag,_g01,v1); pk_hi(ao,_o01,v1); \
    pk_lo(ai,_i23,v2); pk_lo(af,_f23,v2); pk_lo(ag,_g23,v2); pk_lo(ao,_o23,v2); \
    pk_hi(ai,_i23,v3); pk_hi(af,_f23,v3); pk_hi(ag,_g23,v3); pk_hi(ao,_o23,v3); \
}while(0)

static __device__ __forceinline__ float sigm1(float x){
    return __builtin_amdgcn_rcpf(1.0f + __expf(-x));
}
static __device__ __forceinline__ v2f sigm(v2f x){ return mk(sigm1(x.x), sigm1(x.y)); }
static __device__ __forceinline__ float tanh1(float x){
    return 1.0f - 2.0f * __builtin_amdgcn_rcpf(__expf(2.0f * x) + 1.0f);
}
static __device__ __forceinline__ v2f tanhv(v2f x){ return mk(tanh1(x.x), tanh1(x.y)); }

__global__ __launch_bounds__(256)
void lstm_fused(const float* __restrict__ X,
                const int*   __restrict__ pm,
                const float* __restrict__ h0,
                const float* __restrict__ c0,
                const float* __restrict__ Yv,
                const int*   __restrict__ tobs_p,
                const int*   __restrict__ tpred_p,
                const float* __restrict__ W_in,  const float* __restrict__ b_in,
                const float* __restrict__ W_ih,  const float* __restrict__ W_hh,
                const float* __restrict__ b_ih,  const float* __restrict__ b_hh,
                const float* __restrict__ W_out, const float* __restrict__ b_out,
                float* __restrict__ outp, int N)
{
    // ---- LDS-staged weights (rows 16B-aligned; biases pre-summed & dup'd) ----
    __shared__ v4f s_wih[4*H][4];     // W_ih rows padded 10 -> 16 floats
    __shared__ v4f s_whh[4*H][5];     // W_hh rows, 20 floats = 5 quads
    __shared__ v2f s_bias2[4*H];      // {b_ih+b_hh, b_ih+b_hh}
    __shared__ v2f s_win[M];          // W_in row = 2 floats
    __shared__ v2f s_bin2[M];         // {b_in, b_in}
    __shared__ v2f s_wout[2][M];      // row r, pair (2k, 2k+1)
    __shared__ v2f s_bout2[2];        // {b_out, b_out}

    const int lt = threadIdx.x;
    {
        float* f_wih = (float*)s_wih;
        for (int i = lt; i < 4*H*16; i += 256){
            int rr = i >> 4, kk = i & 15;
            f_wih[i] = (kk < M) ? W_ih[rr*M + kk] : 0.f;
        }
        float* f_whh = (float*)s_whh;
        for (int i = lt; i < 4*H*H; i += 256) f_whh[i] = W_hh[i];
        if (lt < 4*H){ float s = b_ih[lt] + b_hh[lt]; s_bias2[lt] = mk(s, s); }
        if (lt < M){ s_win[lt] = mk(W_in[lt*2], W_in[lt*2+1]);
                     float bb = b_in[lt]; s_bin2[lt] = mk(bb, bb); }
        if (lt < 2*M){ int rr = lt / M, k2 = lt % M;
                       s_wout[rr][k2] = mk(W_out[rr*H + 2*k2], W_out[rr*H + 2*k2 + 1]); }
        if (lt < 2){ float bb = b_out[lt]; s_bout2[lt] = mk(bb, bb); }
    }
    __syncthreads();

    const int tid  = blockIdx.x * blockDim.x + lt;
    const int half = N >> 1;
    if (tid >= half) return;          // no barriers after this point
    const int n0 = tid;               // lane's sequence A
    const int n1 = tid + half;        // lane's sequence B
    const int T_obs  = *tobs_p;
    const int T_pred = *tpred_p;
    const int tmax   = (T_pred < TSTEPS - 1) ? T_pred : (TSTEPS - 1);

    // recurrent state in registers (packed: .x = seq A, .y = seq B)
    v2f h[H], c[H];
#pragma unroll
    for (int j = 0; j < H; ++j){
        h[j] = mk(h0[(size_t)n0*H + j], h0[(size_t)n1*H + j]);
        c[j] = mk(c0[(size_t)n0*H + j], c0[(size_t)n1*H + j]);
    }

    v2f q0 = sp(1.f), q1 = sp(1.f), q2 = sp(1.f);   // m_prev3 rolling queue
    v2f po0 = sp(0.f), po1 = sp(0.f);               // prev output

    int pm0 = pm[n0];
    int pm1 = pm[n1];
    v2f x0, x1;
    {
        v2f xa = *(const v2f*)(X + ((size_t)0*N + n0)*4 + 2);
        v2f xb = *(const v2f*)(X + ((size_t)0*N + n1)*4 + 2);
        x0 = mk(xa.x, xb.x);
        x1 = mk(xa.y, xb.y);
    }

    int z = 0;     // laundered zero: defeats LICM of LDS weight reads

#pragma unroll 1
    for (int t = 0; t <= tmax; ++t){
        asm volatile("" : "+v"(z));   // z is 0, but the compiler can't know
        // All LDS bases derive from z -> addresses differ (as far as the
        // compiler knows) every iteration -> loads stay inside the loop.
        const v4f* wih   = &s_wih[z][0];          // row stride 4 quads
        const v4f* whh   = &s_whh[z][0];          // row stride 5 quads
        const v2f* bias2 = &s_bias2[z];
        const v2f* win   = &s_win[z];
        const v2f* bin2  = &s_bin2[z];
        const v2f* wout  = &s_wout[z][0];         // [2][M] row-major
        const v2f* bout2 = &s_bout2[z];

        const v2f mt  = mk((float)pm0, (float)pm1);
        const v2f mp3 = q0; q0 = q1; q1 = q2; q2 = mt;

        v2f in0, in1;
        if (t <= T_obs){ in0 = x0; in1 = x1; }       // uniform branch
        else           { in0 = po0; in1 = po1; }

        // prefetch next step's mask / X
        if (t < tmax){
            pm0 = pm[(size_t)(t+1)*N + n0];
            pm1 = pm[(size_t)(t+1)*N + n1];
            if (t + 1 <= T_obs){
                v2f xa = *(const v2f*)(X + ((size_t)(t+1)*N + n0)*4 + 2);
                v2f xb = *(const v2f*)(X + ((size_t)(t+1)*N + n1)*4 + 2);
                x0 = mk(xa.x, xb.x);
                x1 = mk(xa.y, xb.y);
            }
        }

        // early Y fetch for overwrite lanes
        const bool ow_u = (t > 3) && (t > T_obs);
        bool ow_a = false, ow_b = false;
        v2f y0 = sp(0.f), y1 = sp(0.f);
        if (ow_u){
            ow_a = (mt.x != 0.f) && (mp3.x == 0.f);
            ow_b = (mt.y != 0.f) && (mp3.y == 0.f);
            if (ow_a){ v2f ya = *(const v2f*)(Yv + ((size_t)t*N + n0)*2); y0.x = ya.x; y1.x = ya.y; }
            if (ow_b){ v2f yb = *(const v2f*)(Yv + ((size_t)t*N + n1)*2); y0.y = yb.x; y1.y = yb.y; }
        }

        // ---- r = relu(inp @ W_in.T + b_in) ----
        v2f r[M];
#pragma unroll
        for (int mm = 0; mm < M; ++mm){
            v2f a = bin2[mm];
            v2f w = win[mm];                     // ds_read_b64
            pk_lo(a, w, in0);
            pk_hi(a, w, in1);
            r[mm] = mk(fmaxf(a.x, 0.f), fmaxf(a.y, 0.f));
        }

        // ---- gates + cell update (fully unrolled; LDS imm-offset reads) ----
        v2f hn[H];
#pragma unroll
        for (int jj = 0; jj < H; ++jj){
            v2f ai = bias2[jj];
            v2f af = bias2[H + jj];
            v2f ag = bias2[2*H + jj];
            v2f ao = bias2[3*H + jj];

            // W_ih: k = 0..7 (two quads), then k = 8,9 (b64 tail)
            MAC_QUAD(wih[(jj)*4+0], wih[(H+jj)*4+0], wih[(2*H+jj)*4+0], wih[(3*H+jj)*4+0],
                     r[0], r[1], r[2], r[3]);
            MAC_QUAD(wih[(jj)*4+1], wih[(H+jj)*4+1], wih[(2*H+jj)*4+1], wih[(3*H+jj)*4+1],
                     r[4], r[5], r[6], r[7]);
            {
                v2f wi = *(const v2f*)(wih + (jj)*4 + 2);
                v2f wf = *(const v2f*)(wih + (H+jj)*4 + 2);
                v2f wg = *(const v2f*)(wih + (2*H+jj)*4 + 2);
                v2f wo = *(const v2f*)(wih + (3*H+jj)*4 + 2);
                pk_lo(ai,wi,r[8]); pk_lo(af,wf,r[8]); pk_lo(ag,wg,r[8]); pk_lo(ao,wo,r[8]);
                pk_hi(ai,wi,r[9]); pk_hi(af,wf,r[9]); pk_hi(ag,wg,r[9]); pk_hi(ao,wo,r[9]);
            }
            // W_hh: k = 0..19, five quads
            MAC_QUAD(whh[(jj)*5+0], whh[(H+jj)*5+0], whh[(2*H+jj)*5+0], whh[(3*H+jj)*5+0],
                     h[0], h[1], h[2], h[3]);
            MAC_QUAD(whh[(jj)*5+1], whh[(H+jj)*5+1], whh[(2*H+jj)*5+1], whh[(3*H+jj)*5+1],
                     h[4], h[5], h[6], h[7]);
            MAC_QUAD(whh[(jj)*5+2], whh[(H+jj)*5+2], whh[(2*H+jj)*5+2], whh[(3*H+jj)*5+2],
                     h[8], h[9], h[10], h[11]);
            MAC_QUAD(whh[(jj)*5+3], whh[(H+jj)*5+3], whh[(2*H+jj)*5+3], whh[(3*H+jj)*5+3],
                     h[12], h[13], h[14], h[15]);
            MAC_QUAD(whh[(jj)*5+4], whh[(H+jj)*5+4], whh[(2*H+jj)*5+4], whh[(3*H+jj)*5+4],
                     h[16], h[17], h[18], h[19]);

            const v2f cn = sigm(af) * c[jj] + sigm(ai) * tanhv(ag);
            const v2f hv = sigm(ao) * tanhv(cn);
            c[jj]  = cn;          // loop only covers active steps
            hn[jj] = hv;
        }

        // ---- out = (h_new @ W_out.T + b_out) * m ----
        v2f o0 = bout2[0], o1 = bout2[1];
#pragma unroll
        for (int k2 = 0; k2 < M; ++k2){
            v2f w0 = wout[k2];
            v2f w1 = wout[M + k2];
            const v2f ha = hn[2*k2], hb = hn[2*k2+1];
            pk_lo(o0, w0, ha); pk_lo(o1, w1, ha);
            pk_hi(o0, w0, hb); pk_hi(o1, w1, hb);
        }
        o0 *= mt; o1 *= mt;

        if (ow_a){ o0.x = y0.x; o1.x = y1.x; }
        if (ow_b){ o0.y = y0.y; o1.y = y1.y; }

#pragma unroll
        for (int j = 0; j < H; ++j) h[j] = hn[j];

        *(v2f*)(outp + ((size_t)t*N + n0)*2) = mk(o0.x, o1.x);
        *(v2f*)(outp + ((size_t)t*N + n1)*2) = mk(o0.y, o1.y);
        po0 = o0; po1 = o1;
    }

    // tail: reference zeroes outputs for t > T_pred
#pragma unroll 1
    for (int t = tmax + 1; t < TSTEPS; ++t){
        *(v2f*)(outp + ((size_t)t*N + n0)*2) = sp(0.f);
        *(v2f*)(outp + ((size_t)t*N + n1)*2) = sp(0.f);
    }
}

extern "C" void kernel_launch(void* const* d_in, const int* in_sizes, int n_in,
                              void* d_out, int out_size, void* d_ws, size_t ws_size,
                              hipStream_t stream)
{
    const float* X     = (const float*)d_in[0];
    const int*   pmk   = (const int*)  d_in[1];
    const float* h0    = (const float*)d_in[2];
    const float* c0    = (const float*)d_in[3];
    const float* Yv    = (const float*)d_in[4];
    const int*   tobs  = (const int*)  d_in[5];
    const int*   tpred = (const int*)  d_in[6];
    const float* W_in  = (const float*)d_in[7];
    const float* b_in  = (const float*)d_in[8];
    const float* W_ih  = (const float*)d_in[9];
    const float* W_hh  = (const float*)d_in[10];
    const float* b_ih  = (const float*)d_in[11];
    const float* b_hh  = (const float*)d_in[12];
    const float* W_out = (const float*)d_in[13];
    const float* b_out = (const float*)d_in[14];
    float* outp = (float*)d_out;

    const int N = in_sizes[1] / TSTEPS;   // part_masks is (T,1,N)
    const int threads = N / 2;            // 2 sequences per thread (packed fp32)
    const int block = 256;
    const int grid = (threads + block - 1) / block;

    hipLaunchKernelGGL(lstm_fused, dim3(grid), dim3(block), 0, stream,
                       X, pmk, h0, c0, Yv, tobs, tpred,
                       W_in, b_in, W_ih, W_hh, b_ih, b_hh, W_out, b_out,
                       outp, N);
}